// Round 3
// baseline (20416.368 us; speedup 1.0000x reference)
//
#include <hip/hip_runtime.h>
#include <math.h>

#define B_ 128
#define T_ 512
#define V_ 256
#define H_ 512
#define NBLK_ 128

typedef unsigned short u16;
typedef __attribute__((ext_vector_type(8))) __bf16 bf16x8;
typedef __attribute__((ext_vector_type(4))) float f32x4;

__device__ __forceinline__ float sigf(float x) { return 1.f / (1.f + __expf(-x)); }
__device__ __forceinline__ float tanh_fast(float x) {
    x = fminf(fmaxf(x, -15.f), 15.f);
    float e = __expf(2.f * x);
    return (e - 1.f) / (e + 1.f);
}
__device__ __forceinline__ u16 f2bf(float f) {
    union { float f; unsigned int u; } v; v.f = f;
    unsigned int r = v.u + 0x7FFFu + ((v.u >> 16) & 1u);
    return (u16)(r >> 16);
}

// ---------- prep kernels ----------

__global__ __launch_bounds__(256) void conv_x(u16* __restrict__ dst, const float* __restrict__ x) {
    int tid = blockIdx.x * 256 + threadIdx.x;       // B*T*V
    int k = tid & (V_ - 1);
    int t = (tid >> 8) & (T_ - 1);
    int b = tid >> 17;
    float v = x[tid];
    int lane = (b & 15) | (((k >> 3) & 3) << 4);
    dst[((((size_t)t * 8 + (b >> 4)) * 8) + (k >> 5)) * 512 + (size_t)lane * 8 + (k & 7)] = f2bf(v);
}

__global__ __launch_bounds__(256) void conv_w(u16* __restrict__ dst,
                                              const float* __restrict__ wih,
                                              const float* __restrict__ whh,
                                              int KIN, int Ktot) {
    int tid = blockIdx.x * 256 + threadIdx.x;       // 2048 * Ktot
    int n = tid / Ktot, k = tid - n * Ktot;
    float v = (k < KIN) ? wih[(size_t)n * KIN + k] : whh[(size_t)n * H_ + (k - KIN)];
    int lane = (n & 15) | (((k >> 3) & 3) << 4);
    dst[((size_t)((n >> 4) * (Ktot >> 5) + (k >> 5))) * 512 + (size_t)lane * 8 + (k & 7)] = f2bf(v);
}

__global__ __launch_bounds__(256) void vadd(float* __restrict__ d,
                                            const float* __restrict__ a,
                                            const float* __restrict__ b, int n) {
    int i = blockIdx.x * 256 + threadIdx.x;
    if (i < n) d[i] = a[i] + b[i];
}

// ---------- grid barrier (128 one-wave blocks, all co-resident) ----------
// 2-level monotonic: 8 sub-counters (64B apart) + 1 master. No resets; memset
// once per kernel_launch call keeps graph replays deterministic.
__device__ __forceinline__ void grid_barrier(unsigned* __restrict__ bar, int iter, int blkid) {
    if (threadIdx.x == 0) {
        __threadfence();  // flush this wave's h/c writes agent-wide
        const int g = blkid & 7;
        unsigned old = __hip_atomic_fetch_add(&bar[g * 16], 1u, __ATOMIC_ACQ_REL, __HIP_MEMORY_SCOPE_AGENT);
        if (old == 16u * (unsigned)(iter + 1) - 1u) {
            __hip_atomic_fetch_add(&bar[128], 1u, __ATOMIC_ACQ_REL, __HIP_MEMORY_SCOPE_AGENT);
        }
        while (__hip_atomic_load(&bar[128], __ATOMIC_RELAXED, __HIP_MEMORY_SCOPE_AGENT)
               < 8u * (unsigned)(iter + 1)) {
            __builtin_amdgcn_s_sleep(1);
        }
    }
    __threadfence();  // acquire side: invalidate stale lines before reading peers' h
}

// ---------- one wave, one step: 4 mt-tiles x 4 gates, full K ----------
template <int KCIN, bool IS1>
__device__ __forceinline__ void lstm_wave_step(
    const u16* __restrict__ Ain,     // A source at this t (swizzled)
    const u16* __restrict__ Hin,     // swizzled h state (16 kc)
    const u16* __restrict__ WB,      // B fragments
    const float* __restrict__ bsum,
    u16* __restrict__ Hout,
    u16* __restrict__ Out0row,       // L0 only: Out0swz + t*(8*16*512)
    float* __restrict__ c,
    float* __restrict__ hp,
    int js, int mq, int lane, bool write_hp)
{
    constexpr int KCtot = KCIN + 16;
    const u16* w0 = WB + ((size_t)(js)      * KCtot) * 512 + (size_t)lane * 8;
    const u16* w1 = WB + ((size_t)(32 + js) * KCtot) * 512 + (size_t)lane * 8;
    const u16* w2 = WB + ((size_t)(64 + js) * KCtot) * 512 + (size_t)lane * 8;
    const u16* w3 = WB + ((size_t)(96 + js) * KCtot) * 512 + (size_t)lane * 8;

    const u16* ar[4];
    const u16* hr[4];
    #pragma unroll
    for (int u = 0; u < 4; ++u) {
        const int mt = mq * 4 + u;
        ar[u] = Ain + (size_t)mt * KCIN * 512 + (size_t)lane * 8;
        hr[u] = Hin + (size_t)mt * 16 * 512 + (size_t)lane * 8;
    }

    f32x4 acc[4][4];
    #pragma unroll
    for (int u = 0; u < 4; ++u)
        #pragma unroll
        for (int g = 0; g < 4; ++g) acc[u][g] = (f32x4){0.f, 0.f, 0.f, 0.f};

    #pragma unroll 2
    for (int kc = 0; kc < KCIN; ++kc) {
        bf16x8 b0 = *(const bf16x8*)(w0 + (size_t)kc * 512);
        bf16x8 b1 = *(const bf16x8*)(w1 + (size_t)kc * 512);
        bf16x8 b2 = *(const bf16x8*)(w2 + (size_t)kc * 512);
        bf16x8 b3 = *(const bf16x8*)(w3 + (size_t)kc * 512);
        #pragma unroll
        for (int u = 0; u < 4; ++u) {
            bf16x8 a = *(const bf16x8*)(ar[u] + (size_t)kc * 512);
            acc[u][0] = __builtin_amdgcn_mfma_f32_16x16x32_bf16(a, b0, acc[u][0], 0, 0, 0);
            acc[u][1] = __builtin_amdgcn_mfma_f32_16x16x32_bf16(a, b1, acc[u][1], 0, 0, 0);
            acc[u][2] = __builtin_amdgcn_mfma_f32_16x16x32_bf16(a, b2, acc[u][2], 0, 0, 0);
            acc[u][3] = __builtin_amdgcn_mfma_f32_16x16x32_bf16(a, b3, acc[u][3], 0, 0, 0);
        }
    }
    #pragma unroll 2
    for (int kc = 0; kc < 16; ++kc) {
        bf16x8 b0 = *(const bf16x8*)(w0 + (size_t)(KCIN + kc) * 512);
        bf16x8 b1 = *(const bf16x8*)(w1 + (size_t)(KCIN + kc) * 512);
        bf16x8 b2 = *(const bf16x8*)(w2 + (size_t)(KCIN + kc) * 512);
        bf16x8 b3 = *(const bf16x8*)(w3 + (size_t)(KCIN + kc) * 512);
        #pragma unroll
        for (int u = 0; u < 4; ++u) {
            bf16x8 a = *(const bf16x8*)(hr[u] + (size_t)kc * 512);
            acc[u][0] = __builtin_amdgcn_mfma_f32_16x16x32_bf16(a, b0, acc[u][0], 0, 0, 0);
            acc[u][1] = __builtin_amdgcn_mfma_f32_16x16x32_bf16(a, b1, acc[u][1], 0, 0, 0);
            acc[u][2] = __builtin_amdgcn_mfma_f32_16x16x32_bf16(a, b2, acc[u][2], 0, 0, 0);
            acc[u][3] = __builtin_amdgcn_mfma_f32_16x16x32_bf16(a, b3, acc[u][3], 0, 0, 0);
        }
    }

    const int jl = (js << 4) | (lane & 15);
    const float bi = bsum[jl], bfb = bsum[512 + jl], bgb = bsum[1024 + jl], bob = bsum[1536 + jl];

    #pragma unroll
    for (int u = 0; u < 4; ++u) {
        const int mt = mq * 4 + u;
        const int bb = (mt << 4) | ((lane >> 4) << 2);
        #pragma unroll
        for (int r = 0; r < 4; ++r) {
            const int b_ = bb + r;
            const float vi = sigf(acc[u][0][r] + bi);
            const float vf = sigf(acc[u][1][r] + bfb);
            const float vg = tanh_fast(acc[u][2][r] + bgb);
            const float vo = sigf(acc[u][3][r] + bob);
            const size_t ci = (size_t)b_ * H_ + jl;
            const float cn = vf * c[ci] + vi * vg;
            c[ci] = cn;
            const float hn = vo * tanh_fast(cn);
            const u16 hb = f2bf(hn);
            const size_t so = ((size_t)(mt * 16 + (jl >> 5))) * 512
                            + (size_t)((b_ & 15) | (((jl >> 3) & 3) << 4)) * 8 + (jl & 7);
            Hout[so] = hb;
            if (!IS1) Out0row[so] = hb;
            if (write_hp) hp[ci] = hn;
        }
    }
}

// ---------- persistent pipelined recurrence ----------
// 128 blocks x 64 threads (1 wave). Blocks 0-63: layer0 (t=s); 64-127: layer1 (t=s-1).
// Wave = (js = wl>>1, mt-quad = wl&1).
__global__ __launch_bounds__(64, 1) void lstm_persistent(
    const u16* __restrict__ Xswz, u16* __restrict__ Out0swz,
    const u16* __restrict__ WB0, const u16* __restrict__ WB1,
    const float* __restrict__ bsum0, const float* __restrict__ bsum1,
    u16* __restrict__ H0a, u16* __restrict__ H0b,
    u16* __restrict__ H1a, u16* __restrict__ H1b,
    float* __restrict__ c0, float* __restrict__ c1,
    float* __restrict__ h0p, float* __restrict__ h1p,
    unsigned* __restrict__ bar)
{
    const int wid = blockIdx.x;
    const int lane = threadIdx.x;
    const bool is1 = wid >= 64;
    const int wl = wid & 63;
    const int js = wl >> 1;
    const int mq = wl & 1;

    for (int s = 0; s <= T_; ++s) {
        if (!is1 && s < T_) {
            const int t = s;
            const u16* Hin = (s & 1) ? H0b : H0a;
            u16*      Hout = (s & 1) ? H0a : H0b;
            lstm_wave_step<8, false>(Xswz + (size_t)t * (8 * 8 * 512), Hin, WB0, bsum0,
                                     Hout, Out0swz + (size_t)t * (8 * 16 * 512),
                                     c0, h0p, js, mq, lane, s == T_ - 1);
        } else if (is1 && s >= 1) {
            const int t = s - 1;
            const u16* Hin = (s & 1) ? H1a : H1b;
            u16*      Hout = (s & 1) ? H1b : H1a;
            lstm_wave_step<16, true>(Out0swz + (size_t)t * (8 * 16 * 512), Hin, WB1, bsum1,
                                     Hout, nullptr,
                                     c1, h1p, js, mq, lane, s == T_);
        }
        grid_barrier(bar, s, wid);
    }
}

// ---------- tail kernels ----------
__device__ __forceinline__ float dot4_(float4 a, float4 w, float s) {
    s = fmaf(a.x, w.x, s); s = fmaf(a.y, w.y, s);
    s = fmaf(a.z, w.z, s); s = fmaf(a.w, w.w, s);
    return s;
}

__global__ __launch_bounds__(256) void logits_kernel(
    const float* __restrict__ h1, const float* __restrict__ fc_w,
    const float* __restrict__ fc_b, float* __restrict__ out)
{
    __shared__ float hs[H_];
    const int b = blockIdx.x;
    for (int k = threadIdx.x; k < H_; k += 256) hs[k] = h1[(size_t)b * H_ + k];
    __syncthreads();
    const int v = threadIdx.x;
    const float4* wr = reinterpret_cast<const float4*>(fc_w + (size_t)v * H_);
    const float4* hr = reinterpret_cast<const float4*>(hs);
    float s = 0.f;
    #pragma unroll 8
    for (int k = 0; k < H_ / 4; ++k) s = dot4_(hr[k], wr[k], s);
    out[(size_t)b * V_ + v] = s + fc_b[v];
}

__global__ __launch_bounds__(256) void copy_states(
    const float* __restrict__ h0f, const float* __restrict__ h1f,
    const float* __restrict__ c0, const float* __restrict__ c1,
    float* __restrict__ out)
{
    const int i = blockIdx.x * 256 + threadIdx.x;
    const int NBH = B_ * H_;
    float* base = out + (size_t)B_ * V_;
    base[i] = h0f[i];
    base[NBH + i] = h1f[i];
    base[2 * NBH + i] = c0[i];
    base[3 * NBH + i] = c1[i];
}

extern "C" void kernel_launch(void* const* d_in, const int* in_sizes, int n_in,
                              void* d_out, int out_size, void* d_ws, size_t ws_size,
                              hipStream_t stream) {
    const float* x     = (const float*)d_in[0];
    const float* w_ih0 = (const float*)d_in[1];
    const float* w_hh0 = (const float*)d_in[2];
    const float* b_ih0 = (const float*)d_in[3];
    const float* b_hh0 = (const float*)d_in[4];
    const float* w_ih1 = (const float*)d_in[5];
    const float* w_hh1 = (const float*)d_in[6];
    const float* b_ih1 = (const float*)d_in[7];
    const float* b_hh1 = (const float*)d_in[8];
    const float* fc_w  = (const float*)d_in[9];
    const float* fc_b  = (const float*)d_in[10];
    float* out = (float*)d_out;

    // ---- workspace carve-up ----
    char* p = (char*)d_ws;
    u16* Xswz    = (u16*)p; p += (size_t)512 * 8 * 8 * 512 * 2;    // 32 MB
    u16* Out0swz = (u16*)p; p += (size_t)512 * 8 * 16 * 512 * 2;   // 64 MB
    u16* WB0     = (u16*)p; p += (size_t)128 * 24 * 512 * 2;       // 3 MB
    u16* WB1     = (u16*)p; p += (size_t)128 * 32 * 512 * 2;       // 4 MB
    u16* H0a     = (u16*)p; p += 8 * 16 * 512 * 2;                 // 128 KB
    u16* H1a     = (u16*)p; p += 8 * 16 * 512 * 2;
    u16* H0b     = (u16*)p; p += 8 * 16 * 512 * 2;
    u16* H1b     = (u16*)p; p += 8 * 16 * 512 * 2;
    float* c0    = (float*)p; p += (size_t)B_ * H_ * 4;
    float* c1    = (float*)p; p += (size_t)B_ * H_ * 4;
    float* bsum0 = (float*)p; p += 2048 * 4;
    float* bsum1 = (float*)p; p += 2048 * 4;
    float* h0p   = (float*)p; p += (size_t)B_ * H_ * 4;
    float* h1p   = (float*)p; p += (size_t)B_ * H_ * 4;
    unsigned* bar = (unsigned*)p; p += 4096;

    // ---- init + operand re-layout (graph-replayed each call: deterministic) ----
    hipMemsetAsync(H0a, 0, 2 * 8 * 16 * 512 * 2, stream);          // H0a + H1a
    hipMemsetAsync(c0, 0, 2 * (size_t)B_ * H_ * 4, stream);        // c0 + c1
    hipMemsetAsync(bar, 0, 4096, stream);
    conv_x<<<65536, 256, 0, stream>>>(Xswz, x);
    conv_w<<<(2048 * 768) / 256, 256, 0, stream>>>(WB0, w_ih0, w_hh0, 256, 768);
    conv_w<<<(2048 * 1024) / 256, 256, 0, stream>>>(WB1, w_ih1, w_hh1, 512, 1024);
    vadd<<<8, 256, 0, stream>>>(bsum0, b_ih0, b_hh0, 2048);
    vadd<<<8, 256, 0, stream>>>(bsum1, b_ih1, b_hh1, 2048);

    // ---- persistent pipelined recurrence (one dispatch, 513 grid barriers) ----
    lstm_persistent<<<NBLK_, 64, 0, stream>>>(
        Xswz, Out0swz, WB0, WB1, bsum0, bsum1,
        H0a, H0b, H1a, H1b, c0, c1, h0p, h1p, bar);

    logits_kernel<<<B_, 256, 0, stream>>>(h1p, fc_w, fc_b, out);
    copy_states<<<(B_ * H_) / 256, 256, 0, stream>>>(h0p, h1p, c0, c1, out);
}

// Round 4
// 10965.347 us; speedup vs baseline: 1.8619x; 1.8619x over previous
//
#include <hip/hip_runtime.h>
#include <math.h>

#define B_ 128
#define T_ 512
#define V_ 256
#define H_ 512

typedef unsigned short u16;
typedef unsigned int u32;
typedef __attribute__((ext_vector_type(8))) __bf16 bf16x8;
typedef __attribute__((ext_vector_type(4))) float f32x4;
typedef __attribute__((ext_vector_type(4))) u32 u32x4;

__device__ __forceinline__ float sigf(float x) { return 1.f / (1.f + __expf(-x)); }
__device__ __forceinline__ float tanh_fast(float x) {
    x = fminf(fmaxf(x, -15.f), 15.f);
    float e = __expf(2.f * x);
    return (e - 1.f) / (e + 1.f);
}
__device__ __forceinline__ u16 f2bf(float f) {
    union { float f; unsigned int u; } v; v.f = f;
    unsigned int r = v.u + 0x7FFFu + ((v.u >> 16) & 1u);
    return (u16)(r >> 16);
}

// ---------- prep kernels (verified in rounds 2/3) ----------

// x [B,T,V] f32 -> Xswz[t][mt][kc(8)][512] bf16 (A-fragment order)
__global__ __launch_bounds__(256) void conv_x(u16* __restrict__ dst, const float* __restrict__ x) {
    int tid = blockIdx.x * 256 + threadIdx.x;       // B*T*V
    int k = tid & (V_ - 1);
    int t = (tid >> 8) & (T_ - 1);
    int b = tid >> 17;
    float v = x[tid];
    int lane = (b & 15) | (((k >> 3) & 3) << 4);
    dst[((((size_t)t * 8 + (b >> 4)) * 8) + (k >> 5)) * 512 + (size_t)lane * 8 + (k & 7)] = f2bf(v);
}

// [w_ih | w_hh] -> WB[ntile][kc][lane][8] bf16 (B-fragment order, tile-contiguous)
__global__ __launch_bounds__(256) void conv_w(u16* __restrict__ dst,
                                              const float* __restrict__ wih,
                                              const float* __restrict__ whh,
                                              int KIN, int Ktot) {
    int tid = blockIdx.x * 256 + threadIdx.x;       // 2048 * Ktot
    int n = tid / Ktot, k = tid - n * Ktot;
    float v = (k < KIN) ? wih[(size_t)n * KIN + k] : whh[(size_t)n * H_ + (k - KIN)];
    int lane = (n & 15) | (((k >> 3) & 3) << 4);
    dst[((size_t)((n >> 4) * (Ktot >> 5) + (k >> 5))) * 512 + (size_t)lane * 8 + (k & 7)] = f2bf(v);
}

__global__ __launch_bounds__(256) void vadd(float* __restrict__ d,
                                            const float* __restrict__ a,
                                            const float* __restrict__ b, int n) {
    int i = blockIdx.x * 256 + threadIdx.x;
    if (i < n) d[i] = a[i] + b[i];
}

// ---------- persistent recurrence ----------
// 256 blocks x 128 threads (2 waves). blockIdx = js*8 + (layer*4 + mq):
// each sync group (layer,mq) = 32 js-blocks sharing blockIdx%8 -> same XCD.
// Block owns: 16 hidden cols (js) x 4 gates, 32 batches (mq -> mt pair).
// Weights in LDS (fence-immune), c-state in VGPRs (wave0).
// Wave 0/1 split K in halves; LDS reduction; wave0 does the cell update.

template <int KCA, int KCTOT>
__device__ __forceinline__ void step_body(
    const u16* __restrict__ slabA,   // [8 mt][KCA][512]
    const u16* __restrict__ slabH,   // [8 mt][16][512]
    const u16* __restrict__ WBs,     // LDS [4 g][KCTOT][512]
    f32x4* __restrict__ scr,         // LDS [8][64]
    u16* __restrict__ Hout,
    u16* __restrict__ o0,            // L0: Out0swz slab for t, else nullptr
    float* __restrict__ out,
    float creg[2][4],
    float bi0, float bi1, float bi2, float bi3,
    int mq, int w, int lane, int jl, bool is_last, int layer)
{
    constexpr int KHALF = KCTOT / 2;
    const int kcbase = w * KHALF;
    const int mt0 = mq * 2, mt1 = mt0 + 1;

    f32x4 acc[2][4];
    #pragma unroll
    for (int u = 0; u < 2; ++u)
        #pragma unroll
        for (int g = 0; g < 4; ++g) acc[u][g] = (f32x4){0.f, 0.f, 0.f, 0.f};

    #pragma unroll 4
    for (int i = 0; i < KHALF; ++i) {
        const int kc = kcbase + i;
        const u16* a0p;
        const u16* a1p;
        if (kc < KCA) {
            a0p = slabA + ((size_t)mt0 * KCA + kc) * 512 + (size_t)lane * 8;
            a1p = slabA + ((size_t)mt1 * KCA + kc) * 512 + (size_t)lane * 8;
        } else {
            a0p = slabH + ((size_t)mt0 * 16 + (kc - KCA)) * 512 + (size_t)lane * 8;
            a1p = slabH + ((size_t)mt1 * 16 + (kc - KCA)) * 512 + (size_t)lane * 8;
        }
        bf16x8 a0 = *(const bf16x8*)a0p;
        bf16x8 a1 = *(const bf16x8*)a1p;
        #pragma unroll
        for (int g = 0; g < 4; ++g) {
            bf16x8 bg = *(const bf16x8*)(WBs + ((size_t)(g * KCTOT + kc)) * 512 + (size_t)lane * 8);
            acc[0][g] = __builtin_amdgcn_mfma_f32_16x16x32_bf16(a0, bg, acc[0][g], 0, 0, 0);
            acc[1][g] = __builtin_amdgcn_mfma_f32_16x16x32_bf16(a1, bg, acc[1][g], 0, 0, 0);
        }
    }

    if (w == 1) {
        #pragma unroll
        for (int u = 0; u < 2; ++u)
            #pragma unroll
            for (int g = 0; g < 4; ++g) scr[(u * 4 + g) * 64 + lane] = acc[u][g];
    }
    __syncthreads();
    if (w == 0) {
        #pragma unroll
        for (int u = 0; u < 2; ++u) {
            const int mt = mq * 2 + u;
            const int bb = (mt << 4) | ((lane >> 4) << 2);
            f32x4 pi = scr[(u * 4 + 0) * 64 + lane];
            f32x4 pf = scr[(u * 4 + 1) * 64 + lane];
            f32x4 pg = scr[(u * 4 + 2) * 64 + lane];
            f32x4 po = scr[(u * 4 + 3) * 64 + lane];
            #pragma unroll
            for (int r = 0; r < 4; ++r) {
                const int b_ = bb + r;
                const float vi = sigf(acc[u][0][r] + pi[r] + bi0);
                const float vf = sigf(acc[u][1][r] + pf[r] + bi1);
                const float vg = tanh_fast(acc[u][2][r] + pg[r] + bi2);
                const float vo = sigf(acc[u][3][r] + po[r] + bi3);
                const float cn = vf * creg[u][r] + vi * vg;
                creg[u][r] = cn;
                const float hn = vo * tanh_fast(cn);
                const u16 hb = f2bf(hn);
                const size_t so = ((size_t)(mt * 16 + (jl >> 5))) * 512
                                + (size_t)((b_ & 15) | (((jl >> 3) & 3) << 4)) * 8 + (jl & 7);
                Hout[so] = hb;
                if (o0) o0[so] = hb;
                if (is_last) {
                    const int hbase = layer ? 98304 : 32768;   // 32768 + layer*65536
                    const int cbase = layer ? 229376 : 163840; // 163840 + layer*65536
                    out[hbase + b_ * 512 + jl] = hn;
                    out[cbase + b_ * 512 + jl] = cn;
                }
            }
        }
    }
}

__global__ __launch_bounds__(128, 1) void lstm_persistent(
    const u16* __restrict__ Xswz, u16* __restrict__ Out0swz,
    const u16* __restrict__ WB0, const u16* __restrict__ WB1,
    const float* __restrict__ bsum0, const float* __restrict__ bsum1,
    u16* __restrict__ H0a, u16* __restrict__ H0b,
    u16* __restrict__ H1a, u16* __restrict__ H1b,
    float* __restrict__ out, u32* __restrict__ bar)
{
    __shared__ u16 WBs[4 * 32 * 512];   // 128 KB (L0 uses 4*24*512)
    __shared__ f32x4 scr[8 * 64];       // 8 KB

    const int bid = blockIdx.x;
    const int js = bid >> 3;
    const int grp = bid & 7;            // layer*4 + mq
    const int layer = grp >> 2;
    const int mq = grp & 3;
    const int tid = threadIdx.x;
    const int w = tid >> 6;
    const int lane = tid & 63;

    // ---- one-time LDS weight load ----
    const int KCtot = layer ? 32 : 24;
    const u16* WB = layer ? WB1 : WB0;
    for (int g = 0; g < 4; ++g) {
        const u32x4* s4 = (const u32x4*)(WB + ((size_t)(g * 32 + js) * KCtot) * 512);
        u32x4* d4 = (u32x4*)(WBs + (size_t)g * KCtot * 512);
        for (int i = tid; i < KCtot * 64; i += 128) d4[i] = s4[i];
    }
    __syncthreads();

    const int jl = (js << 4) | (lane & 15);
    const float* bsum = layer ? bsum1 : bsum0;
    const float bi0 = bsum[jl], bi1 = bsum[512 + jl], bi2 = bsum[1024 + jl], bi3 = bsum[1536 + jl];
    float creg[2][4] = {{0.f, 0.f, 0.f, 0.f}, {0.f, 0.f, 0.f, 0.f}};

    // poll pointer: lanes 0..31 watch own group; lanes 32..63 watch L0 pair (L1 only)
    u32* slot_own = bar + grp * 32 + js;
    const u32* pollp;
    bool care;
    if (lane < 32) { pollp = bar + grp * 32 + lane; care = true; }
    else if (layer) { pollp = bar + (grp - 4) * 32 + (lane - 32); care = true; }
    else { pollp = bar + grp * 32 + (lane - 32); care = false; }

    for (int s = 0; s <= T_; ++s) {
        if (s > 0) {
            for (;;) {
                u32 v = __hip_atomic_load(pollp, __ATOMIC_RELAXED, __HIP_MEMORY_SCOPE_AGENT);
                if (__all(!care || (int)v >= s)) break;
                __builtin_amdgcn_s_sleep(2);
            }
            __threadfence();   // acquire: invalidate stale h/out0 lines
        }

        const bool work = layer ? (s >= 1) : (s < T_);
        if (work) {
            const int t = layer ? s - 1 : s;
            if (!layer) {
                const u16* slabH = (s & 1) ? H0b : H0a;
                u16* Hout = (s & 1) ? H0a : H0b;
                step_body<8, 24>(Xswz + (size_t)t * (8 * 8 * 512), slabH, WBs, scr,
                                 Hout, Out0swz + (size_t)t * (8 * 16 * 512), out,
                                 creg, bi0, bi1, bi2, bi3, mq, w, lane, jl,
                                 s == T_ - 1, 0);
            } else {
                const u16* slabH = (s & 1) ? H1a : H1b;
                u16* Hout = (s & 1) ? H1b : H1a;
                step_body<16, 32>(Out0swz + (size_t)t * (8 * 16 * 512), slabH, WBs, scr,
                                  Hout, nullptr, out,
                                  creg, bi0, bi1, bi2, bi3, mq, w, lane, jl,
                                  s == T_, 1);
            }
        }

        if (w == 0) __threadfence();   // release: drain wave0's h/out0 stores
        if (tid == 0)
            __hip_atomic_store(slot_own, (u32)(s + 1), __ATOMIC_RELEASE, __HIP_MEMORY_SCOPE_AGENT);
    }
}

// ---------- tail: logits from h1 final (already in d_out) ----------
__device__ __forceinline__ float dot4_(float4 a, float4 w, float s) {
    s = fmaf(a.x, w.x, s); s = fmaf(a.y, w.y, s);
    s = fmaf(a.z, w.z, s); s = fmaf(a.w, w.w, s);
    return s;
}

__global__ __launch_bounds__(256) void logits_kernel(
    const float* __restrict__ h1, const float* __restrict__ fc_w,
    const float* __restrict__ fc_b, float* __restrict__ out)
{
    __shared__ float hs[H_];
    const int b = blockIdx.x;
    for (int k = threadIdx.x; k < H_; k += 256) hs[k] = h1[(size_t)b * H_ + k];
    __syncthreads();
    const int v = threadIdx.x;
    const float4* wr = reinterpret_cast<const float4*>(fc_w + (size_t)v * H_);
    const float4* hr = reinterpret_cast<const float4*>(hs);
    float s = 0.f;
    #pragma unroll 8
    for (int k = 0; k < H_ / 4; ++k) s = dot4_(hr[k], wr[k], s);
    out[(size_t)b * V_ + v] = s + fc_b[v];
}

extern "C" void kernel_launch(void* const* d_in, const int* in_sizes, int n_in,
                              void* d_out, int out_size, void* d_ws, size_t ws_size,
                              hipStream_t stream) {
    const float* x     = (const float*)d_in[0];
    const float* w_ih0 = (const float*)d_in[1];
    const float* w_hh0 = (const float*)d_in[2];
    const float* b_ih0 = (const float*)d_in[3];
    const float* b_hh0 = (const float*)d_in[4];
    const float* w_ih1 = (const float*)d_in[5];
    const float* w_hh1 = (const float*)d_in[6];
    const float* b_ih1 = (const float*)d_in[7];
    const float* b_hh1 = (const float*)d_in[8];
    const float* fc_w  = (const float*)d_in[9];
    const float* fc_b  = (const float*)d_in[10];
    float* out = (float*)d_out;

    // ---- workspace carve-up ----
    char* p = (char*)d_ws;
    u16* Xswz    = (u16*)p; p += (size_t)512 * 8 * 8 * 512 * 2;    // 32 MB
    u16* Out0swz = (u16*)p; p += (size_t)512 * 8 * 16 * 512 * 2;   // 64 MB
    u16* WB0     = (u16*)p; p += (size_t)128 * 24 * 512 * 2;       // 3 MB
    u16* WB1     = (u16*)p; p += (size_t)128 * 32 * 512 * 2;       // 4 MB
    u16* H0a     = (u16*)p; p += 8 * 16 * 512 * 2;                 // 128 KB
    u16* H1a     = (u16*)p; p += 8 * 16 * 512 * 2;
    u16* H0b     = (u16*)p; p += 8 * 16 * 512 * 2;
    u16* H1b     = (u16*)p; p += 8 * 16 * 512 * 2;
    float* bsum0 = (float*)p; p += 2048 * 4;
    float* bsum1 = (float*)p; p += 2048 * 4;
    u32* bar     = (u32*)p;  p += 8 * 32 * 4;

    // ---- init + operand re-layout (replayed each call: deterministic) ----
    hipMemsetAsync(H0a, 0, 2 * 8 * 16 * 512 * 2, stream);          // H0a + H1a (t=0)
    hipMemsetAsync(bar, 0, 8 * 32 * 4, stream);
    conv_x<<<65536, 256, 0, stream>>>(Xswz, x);
    conv_w<<<(2048 * 768) / 256, 256, 0, stream>>>(WB0, w_ih0, w_hh0, 256, 768);
    conv_w<<<(2048 * 1024) / 256, 256, 0, stream>>>(WB1, w_ih1, w_hh1, 512, 1024);
    vadd<<<8, 256, 0, stream>>>(bsum0, b_ih0, b_hh0, 2048);
    vadd<<<8, 256, 0, stream>>>(bsum1, b_ih1, b_hh1, 2048);

    // ---- persistent pipelined recurrence: one dispatch ----
    lstm_persistent<<<256, 128, 0, stream>>>(
        Xswz, Out0swz, WB0, WB1, bsum0, bsum1,
        H0a, H0b, H1a, H1b, out, bar);

    // logits from h1 final, which lstm_persistent wrote at out+98304
    logits_kernel<<<B_, 256, 0, stream>>>(out + 98304, fc_w, fc_b, out);
}

// Round 5
// 5878.728 us; speedup vs baseline: 3.4729x; 1.8653x over previous
//
#include <hip/hip_runtime.h>
#include <math.h>

#define B_ 128
#define T_ 512
#define V_ 256
#define H_ 512

typedef unsigned short u16;
typedef unsigned int u32;
typedef __attribute__((ext_vector_type(8))) __bf16 bf16x8;
typedef __attribute__((ext_vector_type(4))) float f32x4;
typedef __attribute__((ext_vector_type(4))) u32 u32x4;

__device__ __forceinline__ float sigf(float x) { return 1.f / (1.f + __expf(-x)); }
__device__ __forceinline__ float tanh_fast(float x) {
    x = fminf(fmaxf(x, -15.f), 15.f);
    float e = __expf(2.f * x);
    return (e - 1.f) / (e + 1.f);
}
__device__ __forceinline__ u16 f2bf(float f) {
    union { float f; unsigned int u; } v; v.f = f;
    unsigned int r = v.u + 0x7FFFu + ((v.u >> 16) & 1u);
    return (u16)(r >> 16);
}

// Coherent (agent-scope, L2-bypass/read-through) 16B load as 4 relaxed u32 atomics.
// No cache-maintenance instructions — this is the fence-free cross-XCD path.
__device__ __forceinline__ bf16x8 cohload(const u16* p) {
    u32* q = (u32*)p;
    union { u32 w[4]; bf16x8 v; } u;
    u.w[0] = __hip_atomic_load(q + 0, __ATOMIC_RELAXED, __HIP_MEMORY_SCOPE_AGENT);
    u.w[1] = __hip_atomic_load(q + 1, __ATOMIC_RELAXED, __HIP_MEMORY_SCOPE_AGENT);
    u.w[2] = __hip_atomic_load(q + 2, __ATOMIC_RELAXED, __HIP_MEMORY_SCOPE_AGENT);
    u.w[3] = __hip_atomic_load(q + 3, __ATOMIC_RELAXED, __HIP_MEMORY_SCOPE_AGENT);
    return u.v;
}
__device__ __forceinline__ void cohstore16(u16* p, u16 v) {
    __hip_atomic_store(p, v, __ATOMIC_RELAXED, __HIP_MEMORY_SCOPE_AGENT);
}

// ---------- prep kernels (verified rounds 2-4) ----------

__global__ __launch_bounds__(256) void conv_x(u16* __restrict__ dst, const float* __restrict__ x) {
    int tid = blockIdx.x * 256 + threadIdx.x;       // B*T*V
    int k = tid & (V_ - 1);
    int t = (tid >> 8) & (T_ - 1);
    int b = tid >> 17;
    float v = x[tid];
    int lane = (b & 15) | (((k >> 3) & 3) << 4);
    dst[((((size_t)t * 8 + (b >> 4)) * 8) + (k >> 5)) * 512 + (size_t)lane * 8 + (k & 7)] = f2bf(v);
}

__global__ __launch_bounds__(256) void conv_w(u16* __restrict__ dst,
                                              const float* __restrict__ wih,
                                              const float* __restrict__ whh,
                                              int KIN, int Ktot) {
    int tid = blockIdx.x * 256 + threadIdx.x;       // 2048 * Ktot
    int n = tid / Ktot, k = tid - n * Ktot;
    float v = (k < KIN) ? wih[(size_t)n * KIN + k] : whh[(size_t)n * H_ + (k - KIN)];
    int lane = (n & 15) | (((k >> 3) & 3) << 4);
    dst[((size_t)((n >> 4) * (Ktot >> 5) + (k >> 5))) * 512 + (size_t)lane * 8 + (k & 7)] = f2bf(v);
}

__global__ __launch_bounds__(256) void vadd(float* __restrict__ d,
                                            const float* __restrict__ a,
                                            const float* __restrict__ b, int n) {
    int i = blockIdx.x * 256 + threadIdx.x;
    if (i < n) d[i] = a[i] + b[i];
}

// ---------- persistent recurrence ----------
// 256 blocks x 128 threads (2 waves). blockIdx = js*8 + (layer*4 + mq).
// Block: 16 hidden cols (js) x 4 gates, 32 batches (mt pair mq*2, mq*2+1).
// Weights in LDS, c in VGPRs. Cross-block data via sc-bit atomics, no fences.

template <int KCA, int KCTOT, bool COH_A>
__device__ __forceinline__ void step_body(
    const u16* __restrict__ slabA,   // [8 mt][KCA][512]
    const u16* __restrict__ slabH,   // [8 mt][16][512]
    const u16* __restrict__ WBs,     // LDS [4 g][KCTOT][512]
    f32x4* __restrict__ scr,         // LDS [8][64]
    u16* __restrict__ Hout,
    u16* __restrict__ o0,            // L0: Out0swz slab for t, else nullptr
    float* __restrict__ out,
    float creg[2][4],
    float bi0, float bi1, float bi2, float bi3,
    int mq, int w, int lane, int jl, bool is_last, int layer)
{
    constexpr int KHALF = KCTOT / 2;
    const int kcbase = w * KHALF;
    const int mt0 = mq * 2, mt1 = mt0 + 1;

    f32x4 acc[2][4];
    #pragma unroll
    for (int u = 0; u < 2; ++u)
        #pragma unroll
        for (int g = 0; g < 4; ++g) acc[u][g] = (f32x4){0.f, 0.f, 0.f, 0.f};

    #pragma unroll 4
    for (int i = 0; i < KHALF; ++i) {
        const int kc = kcbase + i;
        bf16x8 a0, a1;
        if (kc < KCA) {
            const u16* a0p = slabA + ((size_t)mt0 * KCA + kc) * 512 + (size_t)lane * 8;
            const u16* a1p = slabA + ((size_t)mt1 * KCA + kc) * 512 + (size_t)lane * 8;
            if (COH_A) { a0 = cohload(a0p); a1 = cohload(a1p); }
            else       { a0 = *(const bf16x8*)a0p; a1 = *(const bf16x8*)a1p; }
        } else {
            a0 = cohload(slabH + ((size_t)mt0 * 16 + (kc - KCA)) * 512 + (size_t)lane * 8);
            a1 = cohload(slabH + ((size_t)mt1 * 16 + (kc - KCA)) * 512 + (size_t)lane * 8);
        }
        #pragma unroll
        for (int g = 0; g < 4; ++g) {
            bf16x8 bg = *(const bf16x8*)(WBs + ((size_t)(g * KCTOT + kc)) * 512 + (size_t)lane * 8);
            acc[0][g] = __builtin_amdgcn_mfma_f32_16x16x32_bf16(a0, bg, acc[0][g], 0, 0, 0);
            acc[1][g] = __builtin_amdgcn_mfma_f32_16x16x32_bf16(a1, bg, acc[1][g], 0, 0, 0);
        }
    }

    if (w == 1) {
        #pragma unroll
        for (int u = 0; u < 2; ++u)
            #pragma unroll
            for (int g = 0; g < 4; ++g) scr[(u * 4 + g) * 64 + lane] = acc[u][g];
    }
    __syncthreads();
    if (w == 0) {
        #pragma unroll
        for (int u = 0; u < 2; ++u) {
            const int mt = mq * 2 + u;
            const int bb = (mt << 4) | ((lane >> 4) << 2);
            f32x4 pi = scr[(u * 4 + 0) * 64 + lane];
            f32x4 pf = scr[(u * 4 + 1) * 64 + lane];
            f32x4 pg = scr[(u * 4 + 2) * 64 + lane];
            f32x4 po = scr[(u * 4 + 3) * 64 + lane];
            #pragma unroll
            for (int r = 0; r < 4; ++r) {
                const int b_ = bb + r;
                const float vi = sigf(acc[u][0][r] + pi[r] + bi0);
                const float vf = sigf(acc[u][1][r] + pf[r] + bi1);
                const float vg = tanh_fast(acc[u][2][r] + pg[r] + bi2);
                const float vo = sigf(acc[u][3][r] + po[r] + bi3);
                const float cn = vf * creg[u][r] + vi * vg;
                creg[u][r] = cn;
                const float hn = vo * tanh_fast(cn);
                const u16 hb = f2bf(hn);
                const size_t so = ((size_t)(mt * 16 + (jl >> 5))) * 512
                                + (size_t)((b_ & 15) | (((jl >> 3) & 3) << 4)) * 8 + (jl & 7);
                cohstore16(Hout + so, hb);
                if (o0) cohstore16(o0 + so, hb);
                if (is_last) {
                    const int hbase = layer ? 98304 : 32768;
                    const int cbase = layer ? 229376 : 163840;
                    out[hbase + b_ * 512 + jl] = hn;
                    out[cbase + b_ * 512 + jl] = cn;
                }
            }
        }
    }
}

__global__ __launch_bounds__(128, 1) void lstm_persistent(
    const u16* __restrict__ Xswz, u16* __restrict__ Out0swz,
    const u16* __restrict__ WB0, const u16* __restrict__ WB1,
    const float* __restrict__ bsum0, const float* __restrict__ bsum1,
    u16* __restrict__ H0a, u16* __restrict__ H0b,
    u16* __restrict__ H1a, u16* __restrict__ H1b,
    float* __restrict__ out, u32* __restrict__ bar)
{
    __shared__ u16 WBs[4 * 32 * 512];   // 128 KB (L0 uses 4*24*512)
    __shared__ f32x4 scr[8 * 64];       // 8 KB

    const int bid = blockIdx.x;
    const int js = bid >> 3;
    const int grp = bid & 7;            // layer*4 + mq
    const int layer = grp >> 2;
    const int mq = grp & 3;
    const int tid = threadIdx.x;
    const int w = tid >> 6;
    const int lane = tid & 63;

    // ---- one-time LDS weight load ----
    const int KCtot = layer ? 32 : 24;
    const u16* WB = layer ? WB1 : WB0;
    for (int g = 0; g < 4; ++g) {
        const u32x4* s4 = (const u32x4*)(WB + ((size_t)(g * 32 + js) * KCtot) * 512);
        u32x4* d4 = (u32x4*)(WBs + (size_t)g * KCtot * 512);
        for (int i = tid; i < KCtot * 64; i += 128) d4[i] = s4[i];
    }
    __syncthreads();

    const int jl = (js << 4) | (lane & 15);
    const float* bsum = layer ? bsum1 : bsum0;
    const float bi0 = bsum[jl], bi1 = bsum[512 + jl], bi2 = bsum[1024 + jl], bi3 = bsum[1536 + jl];
    float creg[2][4] = {{0.f, 0.f, 0.f, 0.f}, {0.f, 0.f, 0.f, 0.f}};

    // poll pointers: lanes 0..31 watch own group; lanes 32..63 watch L0 pair (L1 only)
    u32* slot_own = bar + grp * 32 + js;
    const u32* pollp;
    bool care;
    if (lane < 32) { pollp = bar + grp * 32 + lane; care = true; }
    else if (layer) { pollp = bar + (grp - 4) * 32 + (lane - 32); care = true; }
    else { pollp = bar + grp * 32 + (lane - 32); care = false; }

    for (int s = 0; s <= T_; ++s) {
        if (s > 0) {
            for (;;) {
                u32 v = __hip_atomic_load(pollp, __ATOMIC_RELAXED, __HIP_MEMORY_SCOPE_AGENT);
                if (__all(!care || (int)v >= s)) break;
                __builtin_amdgcn_s_sleep(1);
            }
            __builtin_amdgcn_sched_barrier(0);  // keep data loads below the poll
        }

        const bool work = layer ? (s >= 1) : (s < T_);
        if (work) {
            const int t = layer ? s - 1 : s;
            if (!layer) {
                const u16* slabH = (s & 1) ? H0b : H0a;
                u16* Hout = (s & 1) ? H0a : H0b;
                step_body<8, 24, false>(Xswz + (size_t)t * (8 * 8 * 512), slabH, WBs, scr,
                                        Hout, Out0swz + (size_t)t * (8 * 16 * 512), out,
                                        creg, bi0, bi1, bi2, bi3, mq, w, lane, jl,
                                        s == T_ - 1, 0);
            } else {
                const u16* slabH = (s & 1) ? H1a : H1b;
                u16* Hout = (s & 1) ? H1b : H1a;
                step_body<16, 32, true>(Out0swz + (size_t)t * (8 * 16 * 512), slabH, WBs, scr,
                                        Hout, nullptr, out,
                                        creg, bi0, bi1, bi2, bi3, mq, w, lane, jl,
                                        s == T_, 1);
            }
        }

        // drain this wave's data stores, then post the step flag (no L2 maintenance)
        if (tid == 0) {
            asm volatile("s_waitcnt vmcnt(0)" ::: "memory");
            __hip_atomic_store(slot_own, (u32)(s + 1), __ATOMIC_RELAXED, __HIP_MEMORY_SCOPE_AGENT);
        }
    }
}

// ---------- tail: logits ----------
__device__ __forceinline__ float dot4_(float4 a, float4 w, float s) {
    s = fmaf(a.x, w.x, s); s = fmaf(a.y, w.y, s);
    s = fmaf(a.z, w.z, s); s = fmaf(a.w, w.w, s);
    return s;
}

__global__ __launch_bounds__(256) void logits_kernel(
    const float* __restrict__ h1, const float* __restrict__ fc_w,
    const float* __restrict__ fc_b, float* __restrict__ out)
{
    __shared__ float hs[H_];
    const int b = blockIdx.x;
    for (int k = threadIdx.x; k < H_; k += 256) hs[k] = h1[(size_t)b * H_ + k];
    __syncthreads();
    const int v = threadIdx.x;
    const float4* wr = reinterpret_cast<const float4*>(fc_w + (size_t)v * H_);
    const float4* hr = reinterpret_cast<const float4*>(hs);
    float s = 0.f;
    #pragma unroll 8
    for (int k = 0; k < H_ / 4; ++k) s = dot4_(hr[k], wr[k], s);
    out[(size_t)b * V_ + v] = s + fc_b[v];
}

extern "C" void kernel_launch(void* const* d_in, const int* in_sizes, int n_in,
                              void* d_out, int out_size, void* d_ws, size_t ws_size,
                              hipStream_t stream) {
    const float* x     = (const float*)d_in[0];
    const float* w_ih0 = (const float*)d_in[1];
    const float* w_hh0 = (const float*)d_in[2];
    const float* b_ih0 = (const float*)d_in[3];
    const float* b_hh0 = (const float*)d_in[4];
    const float* w_ih1 = (const float*)d_in[5];
    const float* w_hh1 = (const float*)d_in[6];
    const float* b_ih1 = (const float*)d_in[7];
    const float* b_hh1 = (const float*)d_in[8];
    const float* fc_w  = (const float*)d_in[9];
    const float* fc_b  = (const float*)d_in[10];
    float* out = (float*)d_out;

    // ---- workspace carve-up ----
    char* p = (char*)d_ws;
    u16* Xswz    = (u16*)p; p += (size_t)512 * 8 * 8 * 512 * 2;    // 32 MB
    u16* Out0swz = (u16*)p; p += (size_t)512 * 8 * 16 * 512 * 2;   // 64 MB
    u16* WB0     = (u16*)p; p += (size_t)128 * 24 * 512 * 2;       // 3 MB
    u16* WB1     = (u16*)p; p += (size_t)128 * 32 * 512 * 2;       // 4 MB
    u16* H0a     = (u16*)p; p += 8 * 16 * 512 * 2;                 // 128 KB
    u16* H1a     = (u16*)p; p += 8 * 16 * 512 * 2;
    u16* H0b     = (u16*)p; p += 8 * 16 * 512 * 2;
    u16* H1b     = (u16*)p; p += 8 * 16 * 512 * 2;
    float* bsum0 = (float*)p; p += 2048 * 4;
    float* bsum1 = (float*)p; p += 2048 * 4;
    u32* bar     = (u32*)p;  p += 8 * 32 * 4;

    // ---- init + operand re-layout (replayed each call: deterministic) ----
    hipMemsetAsync(H0a, 0, 2 * 8 * 16 * 512 * 2, stream);          // H0a + H1a (t=0)
    hipMemsetAsync(bar, 0, 8 * 32 * 4, stream);
    conv_x<<<65536, 256, 0, stream>>>(Xswz, x);
    conv_w<<<(2048 * 768) / 256, 256, 0, stream>>>(WB0, w_ih0, w_hh0, 256, 768);
    conv_w<<<(2048 * 1024) / 256, 256, 0, stream>>>(WB1, w_ih1, w_hh1, 512, 1024);
    vadd<<<8, 256, 0, stream>>>(bsum0, b_ih0, b_hh0, 2048);
    vadd<<<8, 256, 0, stream>>>(bsum1, b_ih1, b_hh1, 2048);

    // ---- persistent pipelined recurrence: one dispatch ----
    lstm_persistent<<<256, 128, 0, stream>>>(
        Xswz, Out0swz, WB0, WB1, bsum0, bsum1,
        H0a, H0b, H1a, H1b, out, bar);

    logits_kernel<<<B_, 256, 0, stream>>>(out + 98304, fc_w, fc_b, out);
}

// Round 7
// 3518.830 us; speedup vs baseline: 5.8020x; 1.6706x over previous
//
#include <hip/hip_runtime.h>
#include <math.h>

#define B_ 128
#define T_ 512
#define V_ 256
#define H_ 512

typedef unsigned short u16;
typedef unsigned int u32;
typedef unsigned long long u64;
typedef __attribute__((ext_vector_type(8))) __bf16 bf16x8;
typedef __attribute__((ext_vector_type(4))) float f32x4;
typedef __attribute__((ext_vector_type(4))) u32 u32x4;

__device__ __forceinline__ float sigf(float x) { return 1.f / (1.f + __expf(-x)); }
__device__ __forceinline__ float tanh_fast(float x) {
    x = fminf(fmaxf(x, -15.f), 15.f);
    float e = __expf(2.f * x);
    return (e - 1.f) / (e + 1.f);
}
__device__ __forceinline__ u16 f2bf(float f) {
    union { float f; u32 u; } v; v.f = f;
    u32 r = v.u + 0x7FFFu + ((v.u >> 16) & 1u);
    return (u16)(r >> 16);
}

// ---- proven cross-XCD visibility path (R3-R5): compiler-generated relaxed
// agent-scope atomics only. No fences, no acquire/release (no L2 wb/inv). ----
__device__ __forceinline__ u64 aload(const u64* p) {
    return __hip_atomic_load(p, __ATOMIC_RELAXED, __HIP_MEMORY_SCOPE_AGENT);
}
__device__ __forceinline__ void astore(u64* p, u64 v) {
    __hip_atomic_store(p, v, __ATOMIC_RELAXED, __HIP_MEMORY_SCOPE_AGENT);
}
__device__ __forceinline__ u32 aload32(const u32* p) {
    return __hip_atomic_load(p, __ATOMIC_RELAXED, __HIP_MEMORY_SCOPE_AGENT);
}
__device__ __forceinline__ void astore32(u32* p, u32 v) {
    __hip_atomic_store(p, v, __ATOMIC_RELAXED, __HIP_MEMORY_SCOPE_AGENT);
}
__device__ __forceinline__ void pollge(const u32* slots, int idx, int target) {
    const u32* p = slots + idx;
    for (;;) {
        u32 v = aload32(p);
        if (__all((int)v >= target)) break;
        __builtin_amdgcn_s_sleep(1);
    }
    __builtin_amdgcn_sched_barrier(0);
    asm volatile("" ::: "memory");
}
// 16B fragment via 2 u64 agent atomics
__device__ __forceinline__ bf16x8 afrag(const u16* p) {
    union { u64 d[2]; bf16x8 v; } u;
    u.d[0] = aload((const u64*)p);
    u.d[1] = aload((const u64*)(p + 4));
    return u.v;
}

// ---------- prep kernels (verified rounds 2-5) ----------
__global__ __launch_bounds__(256) void conv_x(u16* __restrict__ dst, const float* __restrict__ x) {
    int tid = blockIdx.x * 256 + threadIdx.x;       // B*T*V
    int k = tid & (V_ - 1);
    int t = (tid >> 8) & (T_ - 1);
    int b = tid >> 17;
    float v = x[tid];
    int lane = (b & 15) | (((k >> 3) & 3) << 4);
    dst[((((size_t)t * 8 + (b >> 4)) * 8) + (k >> 5)) * 512 + (size_t)lane * 8 + (k & 7)] = f2bf(v);
}

__global__ __launch_bounds__(256) void conv_w(u16* __restrict__ dst,
                                              const float* __restrict__ wih,
                                              const float* __restrict__ whh,
                                              int KIN, int Ktot) {
    int tid = blockIdx.x * 256 + threadIdx.x;       // 2048 * Ktot
    int n = tid / Ktot, k = tid - n * Ktot;
    float v = (k < KIN) ? wih[(size_t)n * KIN + k] : whh[(size_t)n * H_ + (k - KIN)];
    int lane = (n & 15) | (((k >> 3) & 3) << 4);
    dst[((size_t)((n >> 4) * (Ktot >> 5) + (k >> 5))) * 512 + (size_t)lane * 8 + (k & 7)] = f2bf(v);
}

__global__ __launch_bounds__(256) void vadd(float* __restrict__ d,
                                            const float* __restrict__ a,
                                            const float* __restrict__ b, int n) {
    int i = blockIdx.x * 256 + threadIdx.x;
    if (i < n) d[i] = a[i] + b[i];
}

// ---------- persistent recurrence ----------
// 256 blocks x 256 threads. blockIdx = js*8 + g, g = layer*4 + mq.
// Block: 16 hidden cols (js), 32 batches (m-tiles 2mq, 2mq+1).
// Wave wid: m = wid&1 (which 16-batch tile), gh = wid>>1 (gate pair: 0->i,f  1->g,o).
// Each wave: 2 gates x full K, acc in 8 VGPRs. gh0 waves do the cell update
// (c in 4 VGPRs) and the coalesced h stores, then post per-(m,js) flags.

template <int LAYER>
__device__ __forceinline__ void run_loop(
    const u16* __restrict__ Xswz, u16* __restrict__ Out0,
    const u16* __restrict__ WBs,          // LDS [4 g][KCT][512]
    f32x4* __restrict__ scr,              // LDS [2 m][2 g][64]
    u16* __restrict__ tile,               // LDS [2 m][16 b][20]
    u16* __restrict__ Hrep,               // [2 phase][2 m][16 hk][512]
    const float* __restrict__ bsum, float* __restrict__ out,
    u32* __restrict__ bl, u32* __restrict__ bc,
    int js, int mq, int wid, int lane)
{
    constexpr int KCA = LAYER ? 16 : 8;
    constexpr int KCT = KCA + 16;
    const int m  = wid & 1;
    const int gh = wid >> 1;
    const int jl = (js << 4) | (lane & 15);
    const float bi0 = bsum[jl],        bi1 = bsum[512 + jl];
    const float bi2 = bsum[1024 + jl], bi3 = bsum[1536 + jl];
    f32x4 creg = {0.f, 0.f, 0.f, 0.f};

    const u16* wb0 = WBs + (size_t)((gh * 2 + 0) * KCT) * 512 + (size_t)lane * 8;
    const u16* wb1 = WBs + (size_t)((gh * 2 + 1) * KCT) * 512 + (size_t)lane * 8;

    for (int s = 0; s <= T_; ++s) {
        const bool work = LAYER ? (s >= 1) : (s < T_);
        const int t = LAYER ? (s - 1) : s;

        f32x4 acc0 = {0.f, 0.f, 0.f, 0.f}, acc1 = {0.f, 0.f, 0.f, 0.f};

        if (work) {
            // ---- A phase (x: plain cached; out0: cross-XCD atomics, flag 1 step old) ----
            if (LAYER == 0) {
                const u16* As = Xswz + (size_t)t * 32768 + (size_t)(2 * mq + m) * 4096 + (size_t)lane * 8;
                #pragma unroll
                for (int kc = 0; kc < 8; ++kc) {
                    bf16x8 a = *(const bf16x8*)(As + (size_t)kc * 512);
                    acc0 = __builtin_amdgcn_mfma_f32_16x16x32_bf16(a, *(const bf16x8*)(wb0 + (size_t)kc * 512), acc0, 0, 0, 0);
                    acc1 = __builtin_amdgcn_mfma_f32_16x16x32_bf16(a, *(const bf16x8*)(wb1 + (size_t)kc * 512), acc1, 0, 0, 0);
                }
            } else {
                pollge(bc, m * 32 + (lane & 31), s);
                const u16* As = Out0 + (size_t)t * 65536 + (size_t)(2 * mq + m) * 8192 + (size_t)lane * 8;
                bf16x8 fa[16];
                #pragma unroll
                for (int kc = 0; kc < 16; ++kc) fa[kc] = afrag(As + (size_t)kc * 512);
                #pragma unroll
                for (int kc = 0; kc < 16; ++kc) {
                    acc0 = __builtin_amdgcn_mfma_f32_16x16x32_bf16(fa[kc], *(const bf16x8*)(wb0 + (size_t)kc * 512), acc0, 0, 0, 0);
                    acc1 = __builtin_amdgcn_mfma_f32_16x16x32_bf16(fa[kc], *(const bf16x8*)(wb1 + (size_t)kc * 512), acc1, 0, 0, 0);
                }
            }
            // ---- H phase (recurrent; the only critical-path wait) ----
            pollge(bl, m * 32 + (lane & 31), s);
            const u16* Hs = Hrep + (size_t)(t & 1) * 16384 + (size_t)m * 8192 + (size_t)lane * 8;
            bf16x8 fh[16];
            #pragma unroll
            for (int hk = 0; hk < 16; ++hk) fh[hk] = afrag(Hs + (size_t)hk * 512);
            #pragma unroll
            for (int hk = 0; hk < 16; ++hk) {
                acc0 = __builtin_amdgcn_mfma_f32_16x16x32_bf16(fh[hk], *(const bf16x8*)(wb0 + (size_t)(KCA + hk) * 512), acc0, 0, 0, 0);
                acc1 = __builtin_amdgcn_mfma_f32_16x16x32_bf16(fh[hk], *(const bf16x8*)(wb1 + (size_t)(KCA + hk) * 512), acc1, 0, 0, 0);
            }
        }

        // ---- gate exchange: gh1 (g,o) -> gh0 (i,f) ----
        if (gh == 1 && work) {
            scr[(m * 2 + 0) * 64 + lane] = acc0;
            scr[(m * 2 + 1) * 64 + lane] = acc1;
        }
        __syncthreads();

        if (gh == 0) {
            if (work) {
                f32x4 pg = scr[(m * 2 + 0) * 64 + lane];
                f32x4 po = scr[(m * 2 + 1) * 64 + lane];
                const bool is_last = (s == (LAYER ? T_ : T_ - 1));
                const int bb = (lane >> 4) << 2;
                u16* tl = tile + (size_t)m * 320;          // [16][20]
                #pragma unroll
                for (int r = 0; r < 4; ++r) {
                    const int b_ = bb + r;
                    const float vi = sigf(acc0[r] + bi0);
                    const float vf = sigf(acc1[r] + bi1);
                    const float vg = tanh_fast(pg[r] + bi2);
                    const float vo = sigf(po[r] + bi3);
                    const float cn = vf * creg[r] + vi * vg;
                    creg[r] = cn;
                    const float hn = vo * tanh_fast(cn);
                    tl[(size_t)b_ * 20 + (lane & 15)] = f2bf(hn);
                    if (is_last) {
                        const int bg = mq * 32 + m * 16 + b_;
                        out[(LAYER ? 98304 : 32768) + bg * 512 + jl] = hn;
                        out[(LAYER ? 229376 : 163840) + bg * 512 + jl] = cn;
                    }
                }
                // coalesced 8B stores of the transposed tile (512B contiguous per m)
                const int c = lane >> 1, half = lane & 1;
                const int b16 = c & 15, jhi = (c >> 4) & 1;
                const int hi = 2 * (js & 1) + jhi;
                u64 v = *(const u64*)(tl + (size_t)b16 * 20 + jhi * 8 + half * 4);
                const size_t eo = (size_t)(m * 16 + (js >> 1)) * 512 + (size_t)((b16 | (hi << 4)) * 8 + half * 4);
                astore((u64*)(Hrep + (size_t)((t & 1) ^ 1) * 16384 + eo), v);
                if (LAYER == 0)
                    astore((u64*)(Out0 + (size_t)t * 65536 + (size_t)(2 * mq + m) * 8192
                                  + (size_t)(js >> 1) * 512 + (size_t)((b16 | (hi << 4)) * 8 + half * 4)), v);
            }
            // drain own stores, then post flags (posted EVERY step, work or not)
            asm volatile("s_waitcnt vmcnt(0)" ::: "memory");
            if (lane == 0) {
                astore32(bl + m * 32 + js, (u32)(s + 1));
                if (LAYER == 0) astore32(bc + m * 32 + js, (u32)(s + 1));
            }
        }
    }
}

__global__ __launch_bounds__(256, 1) void lstm_persistent(
    const u16* __restrict__ Xswz, u16* __restrict__ Out0swz,
    const u16* __restrict__ WB0, const u16* __restrict__ WB1,
    const float* __restrict__ bsum0, const float* __restrict__ bsum1,
    u16* __restrict__ Hbuf, float* __restrict__ out,
    u32* __restrict__ bar_local, u32* __restrict__ bar_cross)
{
    __shared__ u16 WBs[4 * 32 * 512];           // 128 KB (L0 uses 4*24*512)
    __shared__ f32x4 scr[4 * 64];               // 4 KB
    __shared__ __align__(16) u16 tile[2 * 16 * 20];  // 1.25 KB

    const int bid = blockIdx.x;
    const int g = bid & 7, js = bid >> 3;
    const int layer = g >> 2, mq = g & 3;
    const int tid = threadIdx.x;
    const int wid = tid >> 6, lane = tid & 63;

    const int KCtot = layer ? 32 : 24;
    const u16* WB = layer ? WB1 : WB0;
    for (int gg = 0; gg < 4; ++gg) {
        const u32x4* s4 = (const u32x4*)(WB + ((size_t)(gg * 32 + js) * KCtot) * 512);
        u32x4* d4 = (u32x4*)(WBs + (size_t)gg * KCtot * 512);
        for (int i = tid; i < KCtot * 64; i += 256) d4[i] = s4[i];
    }
    __syncthreads();

    u16* Hrep = Hbuf + (size_t)g * 32768;       // [2 phase][16384]
    u32* bl = bar_local + g * 64;
    u32* bc = bar_cross + mq * 64;

    if (layer == 0)
        run_loop<0>(Xswz, Out0swz, WBs, scr, tile, Hrep, bsum0, out, bl, bc, js, mq, wid, lane);
    else
        run_loop<1>(Xswz, Out0swz, WBs, scr, tile, Hrep, bsum1, out, bl, bc, js, mq, wid, lane);
}

// ---------- tail: logits ----------
__device__ __forceinline__ float dot4_(float4 a, float4 w, float s) {
    s = fmaf(a.x, w.x, s); s = fmaf(a.y, w.y, s);
    s = fmaf(a.z, w.z, s); s = fmaf(a.w, w.w, s);
    return s;
}

__global__ __launch_bounds__(256) void logits_kernel(
    const float* __restrict__ h1, const float* __restrict__ fc_w,
    const float* __restrict__ fc_b, float* __restrict__ out)
{
    __shared__ float hs[H_];
    const int b = blockIdx.x;
    for (int k = threadIdx.x; k < H_; k += 256) hs[k] = h1[(size_t)b * H_ + k];
    __syncthreads();
    const int v = threadIdx.x;
    const float4* wr = reinterpret_cast<const float4*>(fc_w + (size_t)v * H_);
    const float4* hr = reinterpret_cast<const float4*>(hs);
    float s = 0.f;
    #pragma unroll 8
    for (int k = 0; k < H_ / 4; ++k) s = dot4_(hr[k], wr[k], s);
    out[(size_t)b * V_ + v] = s + fc_b[v];
}

extern "C" void kernel_launch(void* const* d_in, const int* in_sizes, int n_in,
                              void* d_out, int out_size, void* d_ws, size_t ws_size,
                              hipStream_t stream) {
    const float* x     = (const float*)d_in[0];
    const float* w_ih0 = (const float*)d_in[1];
    const float* w_hh0 = (const float*)d_in[2];
    const float* b_ih0 = (const float*)d_in[3];
    const float* b_hh0 = (const float*)d_in[4];
    const float* w_ih1 = (const float*)d_in[5];
    const float* w_hh1 = (const float*)d_in[6];
    const float* b_ih1 = (const float*)d_in[7];
    const float* b_hh1 = (const float*)d_in[8];
    const float* fc_w  = (const float*)d_in[9];
    const float* fc_b  = (const float*)d_in[10];
    float* out = (float*)d_out;

    // ---- workspace carve-up ----
    char* p = (char*)d_ws;
    u16* Xswz    = (u16*)p; p += (size_t)512 * 32768 * 2;          // 32 MB
    u16* Out0swz = (u16*)p; p += (size_t)512 * 65536 * 2;          // 64 MB
    u16* WB0     = (u16*)p; p += (size_t)128 * 24 * 512 * 2;       // 3 MB
    u16* WB1     = (u16*)p; p += (size_t)128 * 32 * 512 * 2;       // 4 MB
    u16* Hbuf    = (u16*)p; p += (size_t)8 * 32768 * 2;            // 512 KB
    float* bsum0 = (float*)p; p += 2048 * 4;
    float* bsum1 = (float*)p; p += 2048 * 4;
    u32* bar_local = (u32*)p; p += 8 * 64 * 4;                     // 2 KB
    u32* bar_cross = (u32*)p; p += 4 * 64 * 4;                     // 1 KB

    // ---- init + operand re-layout (graph-replayed each call: deterministic) ----
    hipMemsetAsync(Hbuf, 0, (size_t)8 * 32768 * 2, stream);        // h(-1) = 0 (both phases)
    hipMemsetAsync(bar_local, 0, 8 * 64 * 4 + 4 * 64 * 4, stream); // flags (adjacent)
    conv_x<<<65536, 256, 0, stream>>>(Xswz, x);
    conv_w<<<(2048 * 768) / 256, 256, 0, stream>>>(WB0, w_ih0, w_hh0, 256, 768);
    conv_w<<<(2048 * 1024) / 256, 256, 0, stream>>>(WB1, w_ih1, w_hh1, 512, 1024);
    vadd<<<8, 256, 0, stream>>>(bsum0, b_ih0, b_hh0, 2048);
    vadd<<<8, 256, 0, stream>>>(bsum1, b_ih1, b_hh1, 2048);

    // ---- persistent pipelined recurrence: one dispatch ----
    lstm_persistent<<<256, 256, 0, stream>>>(
        Xswz, Out0swz, WB0, WB1, bsum0, bsum1,
        Hbuf, out, bar_local, bar_cross);

    logits_kernel<<<B_, 256, 0, stream>>>(out + 98304, fc_w, fc_b, out);
}

// Round 8
// 3213.662 us; speedup vs baseline: 6.3530x; 1.0950x over previous
//
#include <hip/hip_runtime.h>
#include <math.h>

#define B_ 128
#define T_ 512
#define V_ 256
#define H_ 512

typedef unsigned short u16;
typedef unsigned int u32;
typedef unsigned long long u64;
typedef __attribute__((ext_vector_type(8))) __bf16 bf16x8;
typedef __attribute__((ext_vector_type(4))) float f32x4;
typedef __attribute__((ext_vector_type(4))) u32 u32x4;

__device__ __forceinline__ float sigf(float x) { return 1.f / (1.f + __expf(-x)); }
__device__ __forceinline__ float tanh_fast(float x) {
    x = fminf(fmaxf(x, -15.f), 15.f);
    float e = __expf(2.f * x);
    return (e - 1.f) / (e + 1.f);
}
__device__ __forceinline__ u16 f2bf(float f) {
    union { float f; u32 u; } v; v.f = f;
    u32 r = v.u + 0x7FFFu + ((v.u >> 16) & 1u);
    return (u16)(r >> 16);
}

// proven cross-XCD visibility path: compiler-generated relaxed agent atomics
__device__ __forceinline__ u64 aload(const u64* p) {
    return __hip_atomic_load(p, __ATOMIC_RELAXED, __HIP_MEMORY_SCOPE_AGENT);
}
__device__ __forceinline__ void astore(u64* p, u64 v) {
    __hip_atomic_store(p, v, __ATOMIC_RELAXED, __HIP_MEMORY_SCOPE_AGENT);
}
__device__ __forceinline__ u32 aload32(const u32* p) {
    return __hip_atomic_load(p, __ATOMIC_RELAXED, __HIP_MEMORY_SCOPE_AGENT);
}
__device__ __forceinline__ void astore32(u32* p, u32 v) {
    __hip_atomic_store(p, v, __ATOMIC_RELAXED, __HIP_MEMORY_SCOPE_AGENT);
}
__device__ __forceinline__ void pollge(const u32* slots, int idx, int target) {
    const u32* p = slots + idx;
    for (;;) {
        u32 v = aload32(p);
        if (__all((int)v >= target)) break;
        __builtin_amdgcn_s_sleep(1);
    }
    __builtin_amdgcn_sched_barrier(0);
    asm volatile("" ::: "memory");
}
__device__ __forceinline__ bf16x8 afrag(const u16* p) {
    union { u64 d[2]; bf16x8 v; } u;
    u.d[0] = aload((const u64*)p);
    u.d[1] = aload((const u64*)(p + 4));
    return u.v;
}

// ---------- prep kernels (verified rounds 2-7) ----------
__global__ __launch_bounds__(256) void conv_x(u16* __restrict__ dst, const float* __restrict__ x) {
    int tid = blockIdx.x * 256 + threadIdx.x;
    int k = tid & (V_ - 1);
    int t = (tid >> 8) & (T_ - 1);
    int b = tid >> 17;
    float v = x[tid];
    int lane = (b & 15) | (((k >> 3) & 3) << 4);
    dst[((((size_t)t * 8 + (b >> 4)) * 8) + (k >> 5)) * 512 + (size_t)lane * 8 + (k & 7)] = f2bf(v);
}

__global__ __launch_bounds__(256) void conv_w(u16* __restrict__ dst,
                                              const float* __restrict__ wih,
                                              const float* __restrict__ whh,
                                              int KIN, int Ktot) {
    int tid = blockIdx.x * 256 + threadIdx.x;
    int n = tid / Ktot, k = tid - n * Ktot;
    float v = (k < KIN) ? wih[(size_t)n * KIN + k] : whh[(size_t)n * H_ + (k - KIN)];
    int lane = (n & 15) | (((k >> 3) & 3) << 4);
    dst[((size_t)((n >> 4) * (Ktot >> 5) + (k >> 5))) * 512 + (size_t)lane * 8 + (k & 7)] = f2bf(v);
}

__global__ __launch_bounds__(256) void vadd(float* __restrict__ d,
                                            const float* __restrict__ a,
                                            const float* __restrict__ b, int n) {
    int i = blockIdx.x * 256 + threadIdx.x;
    if (i < n) d[i] = a[i] + b[i];
}

// ---------- persistent recurrence ----------
// 256 blocks x 256 threads. blockIdx = js*8 + g, g = layer*4 + mq.
// Waves: wid 0,1 = A-role (m=wid): x/out0 MFMAs. wid 2,3 = H-role (m=wid-2):
// tagged-h poll + recurrent MFMAs + cell update + tagged stores.
// h element = u32 (tag<<16 | bf16); u64 atomic store => per-u64 tag consistency.
// h(t) stored at buf (t+1)&1 with tag t+1; consumer expects tag==t_prev+1.

template <int LAYER>
__device__ __forceinline__ void run_loop(
    const u16* __restrict__ Xswz, u16* __restrict__ Out0,
    const u16* __restrict__ WBs,          // LDS [4 g][KCT][512] bf16
    f32x4* __restrict__ scr,              // LDS [2 m][4 g][64]
    u16* __restrict__ tileb,              // LDS [2 m][16][20]
    u32* __restrict__ Hgrp,               // [2 buf][2 m][16 kc][512] tagged u32
    const float* __restrict__ bsum, float* __restrict__ out,
    u32* __restrict__ bc,                 // [2 m][32 js] (this mq)
    int js, int mq, int wid, int lane)
{
    constexpr int KCA = LAYER ? 16 : 8;
    constexpr int KCT = KCA + 16;
    const int m = wid & 1;
    const bool isA = wid < 2;
    const int jl = (js << 4) | (lane & 15);

    if (isA) {
        // ---------------- A-role wave ----------------
        for (int s = 0; s <= T_; ++s) {
            const bool work = LAYER ? (s >= 1) : (s < T_);
            const int t = LAYER ? (s - 1) : s;
            if (work) {
                f32x4 acc[4];
                #pragma unroll
                for (int g = 0; g < 4; ++g) acc[g] = (f32x4){0.f, 0.f, 0.f, 0.f};
                if (LAYER == 0) {
                    const u16* As = Xswz + (size_t)t * 32768 + (size_t)(2 * mq + m) * 4096 + (size_t)lane * 8;
                    #pragma unroll
                    for (int kc = 0; kc < 8; ++kc) {
                        bf16x8 a = *(const bf16x8*)(As + (size_t)kc * 512);
                        #pragma unroll
                        for (int g = 0; g < 4; ++g)
                            acc[g] = __builtin_amdgcn_mfma_f32_16x16x32_bf16(
                                a, *(const bf16x8*)(WBs + (size_t)(g * KCT + kc) * 512 + (size_t)lane * 8), acc[g], 0, 0, 0);
                    }
                } else {
                    pollge(bc + m * 32, lane & 31, s);
                    const u16* As = Out0 + (size_t)t * 65536 + (size_t)(2 * mq + m) * 8192 + (size_t)lane * 8;
                    bf16x8 fa[16];
                    #pragma unroll
                    for (int kc = 0; kc < 16; ++kc) fa[kc] = afrag(As + (size_t)kc * 512);
                    #pragma unroll
                    for (int kc = 0; kc < 16; ++kc) {
                        #pragma unroll
                        for (int g = 0; g < 4; ++g)
                            acc[g] = __builtin_amdgcn_mfma_f32_16x16x32_bf16(
                                fa[kc], *(const bf16x8*)(WBs + (size_t)(g * KCT + kc) * 512 + (size_t)lane * 8), acc[g], 0, 0, 0);
                    }
                }
                #pragma unroll
                for (int g = 0; g < 4; ++g) scr[(m * 4 + g) * 64 + lane] = acc[g];
            }
            __syncthreads();   // sync1: scr ready for H
            __syncthreads();   // sync2: H consumed scr
        }
    } else {
        // ---------------- H-role wave ----------------
        const float bi0 = bsum[jl], bi1 = bsum[512 + jl];
        const float bi2 = bsum[1024 + jl], bi3 = bsum[1536 + jl];
        f32x4 creg = {0.f, 0.f, 0.f, 0.f};
        u32* bcs = bc + m * 32 + js;

        for (int s = 0; s <= T_; ++s) {
            const bool work = LAYER ? (s >= 1) : (s < T_);
            const int t = LAYER ? (s - 1) : s;
            f32x4 acc[4];
            #pragma unroll
            for (int g = 0; g < 4; ++g) acc[g] = (f32x4){0.f, 0.f, 0.f, 0.f};
            u64 f[64];

            if (work) {
                const u32 tag = (u32)(LAYER ? (s - 1) : s);           // expected tag
                const u32* hb = Hgrp + (size_t)(tag & 1) * 16384 + (size_t)m * 8192;
                // head pre-poll: one u64 per 512B producer chunk (64 chunks)
                {
                    const u64* hp = (const u64*)(hb + (size_t)lane * 128);
                    for (;;) {
                        u64 d = aload(hp);
                        if (__all(((u32)(d >> 16) & 0xFFFFu) == tag)) break;
                        __builtin_amdgcn_s_sleep(1);
                    }
                }
                // full load + verify (tags within each u64 are store-atomic)
                for (;;) {
                    #pragma unroll
                    for (int kc = 0; kc < 16; ++kc) {
                        const u64* p = (const u64*)(hb + (size_t)kc * 512 + (size_t)lane * 8);
                        f[4 * kc + 0] = aload(p + 0);
                        f[4 * kc + 1] = aload(p + 1);
                        f[4 * kc + 2] = aload(p + 2);
                        f[4 * kc + 3] = aload(p + 3);
                    }
                    u32 bad = 0;
                    #pragma unroll
                    for (int i = 0; i < 64; ++i) bad |= (((u32)(f[i] >> 16)) & 0xFFFFu) ^ tag;
                    if (!__any(bad != 0u)) break;
                    __builtin_amdgcn_s_sleep(1);
                }
                __builtin_amdgcn_sched_barrier(0);
            }
            // L0: post out0-ready flag; poll above already drained vmcnt (stores incl.)
            if (LAYER == 0 && s > 0) {
                if (!work) asm volatile("s_waitcnt vmcnt(0)" ::: "memory");
                if (lane == 0) astore32(bcs, (u32)s);
            }
            if (work) {
                #pragma unroll
                for (int kc = 0; kc < 16; ++kc) {
                    u32 w0 = (u32)(f[4 * kc + 0] & 0xFFFFu) | ((u32)(f[4 * kc + 0] >> 32) << 16);
                    u32 w1 = (u32)(f[4 * kc + 1] & 0xFFFFu) | ((u32)(f[4 * kc + 1] >> 32) << 16);
                    u32 w2 = (u32)(f[4 * kc + 2] & 0xFFFFu) | ((u32)(f[4 * kc + 2] >> 32) << 16);
                    u32 w3 = (u32)(f[4 * kc + 3] & 0xFFFFu) | ((u32)(f[4 * kc + 3] >> 32) << 16);
                    u32x4 ww = {w0, w1, w2, w3};
                    bf16x8 a = __builtin_bit_cast(bf16x8, ww);
                    #pragma unroll
                    for (int g = 0; g < 4; ++g)
                        acc[g] = __builtin_amdgcn_mfma_f32_16x16x32_bf16(
                            a, *(const bf16x8*)(WBs + (size_t)(g * KCT + KCA + kc) * 512 + (size_t)lane * 8), acc[g], 0, 0, 0);
                }
            }
            __syncthreads();   // sync1
            if (work) {
                #pragma unroll
                for (int g = 0; g < 4; ++g) acc[g] += scr[(m * 4 + g) * 64 + lane];
            }
            __syncthreads();   // sync2
            if (work) {
                const bool is_last = (s == (LAYER ? T_ : T_ - 1));
                const int bb = (lane >> 4) << 2;
                #pragma unroll
                for (int r = 0; r < 4; ++r) {
                    const float vi = sigf(acc[0][r] + bi0);
                    const float vf = sigf(acc[1][r] + bi1);
                    const float vg = tanh_fast(acc[2][r] + bi2);
                    const float vo = sigf(acc[3][r] + bi3);
                    const float cn = vf * creg[r] + vi * vg;
                    creg[r] = cn;
                    const float hn = vo * tanh_fast(cn);
                    tileb[(size_t)(m * 16 + bb + r) * 20 + (lane & 15)] = f2bf(hn);
                    if (is_last) {
                        const int bg = mq * 32 + m * 16 + bb + r;
                        out[(LAYER ? 98304 : 32768) + bg * 512 + jl] = hn;
                        out[(LAYER ? 229376 : 163840) + bg * 512 + jl] = cn;
                    }
                }
                // tagged h store: 2 chunks x 128 u32, wave-coalesced u64 stores
                const u32 wtag = (u32)(t + 1);
                u32* hw = Hgrp + (size_t)(wtag & 1) * 16384 + (size_t)m * 8192;
                #pragma unroll
                for (int q = 0; q < 2; ++q) {
                    u32 w = *(const u32*)&tileb[(size_t)(m * 16 + (lane >> 2)) * 20 + q * 8 + (lane & 3) * 2];
                    u64 v = (u64)(w & 0xFFFFu) | ((u64)wtag << 16)
                          | ((u64)(w >> 16) << 32) | ((u64)wtag << 48);
                    astore((u64*)(hw + (size_t)(js >> 1) * 512 + (size_t)((js & 1) * 2 + q) * 128
                                  + (size_t)(lane >> 2) * 8 + (size_t)((lane & 3) * 2)), v);
                }
                if (LAYER == 0) {
                    const int q2 = lane >> 5, lw = lane & 31, b2 = lw >> 1, e4 = (lw & 1) * 4;
                    u64 v = *(const u64*)&tileb[(size_t)(m * 16 + b2) * 20 + q2 * 8 + e4];
                    astore((u64*)(Out0 + (size_t)t * 65536 + (size_t)(2 * mq + m) * 8192
                                  + (size_t)(js >> 1) * 512 + (size_t)((js & 1) * 2 + q2) * 128
                                  + (size_t)b2 * 8 + (size_t)e4), v);
                }
            }
        }
    }
}

__global__ __launch_bounds__(256, 1) void lstm_persistent(
    const u16* __restrict__ Xswz, u16* __restrict__ Out0swz,
    const u16* __restrict__ WB0, const u16* __restrict__ WB1,
    const float* __restrict__ bsum0, const float* __restrict__ bsum1,
    u32* __restrict__ Htag, float* __restrict__ out, u32* __restrict__ bc)
{
    __shared__ u16 WBs[4 * 32 * 512];                 // 128 KB
    __shared__ f32x4 scr[2 * 4 * 64];                 // 8 KB
    __shared__ __align__(16) u16 tileb[2 * 16 * 20];  // 1.25 KB

    const int bid = blockIdx.x;
    const int g = bid & 7, js = bid >> 3;
    const int layer = g >> 2, mq = g & 3;
    const int tid = threadIdx.x;
    const int wid = tid >> 6, lane = tid & 63;

    const int KCtot = layer ? 32 : 24;
    const u16* WB = layer ? WB1 : WB0;
    for (int gg = 0; gg < 4; ++gg) {
        const u32x4* s4 = (const u32x4*)(WB + ((size_t)(gg * 32 + js) * KCtot) * 512);
        u32x4* d4 = (u32x4*)(WBs + (size_t)gg * KCtot * 512);
        for (int i = tid; i < KCtot * 64; i += 256) d4[i] = s4[i];
    }
    __syncthreads();

    u32* Hgrp = Htag + (size_t)g * 32768;   // [2 buf][2 m][16 kc][512]
    u32* bcg = bc + mq * 64;                // [2 m][32 js]

    if (layer == 0)
        run_loop<0>(Xswz, Out0swz, WBs, scr, tileb, Hgrp, bsum0, out, bcg, js, mq, wid, lane);
    else
        run_loop<1>(Xswz, Out0swz, WBs, scr, tileb, Hgrp, bsum1, out, bcg, js, mq, wid, lane);
}

// ---------- tail: logits ----------
__device__ __forceinline__ float dot4_(float4 a, float4 w, float s) {
    s = fmaf(a.x, w.x, s); s = fmaf(a.y, w.y, s);
    s = fmaf(a.z, w.z, s); s = fmaf(a.w, w.w, s);
    return s;
}

__global__ __launch_bounds__(256) void logits_kernel(
    const float* __restrict__ h1, const float* __restrict__ fc_w,
    const float* __restrict__ fc_b, float* __restrict__ out)
{
    __shared__ float hs[H_];
    const int b = blockIdx.x;
    for (int k = threadIdx.x; k < H_; k += 256) hs[k] = h1[(size_t)b * H_ + k];
    __syncthreads();
    const int v = threadIdx.x;
    const float4* wr = reinterpret_cast<const float4*>(fc_w + (size_t)v * H_);
    const float4* hr = reinterpret_cast<const float4*>(hs);
    float s = 0.f;
    #pragma unroll 8
    for (int k = 0; k < H_ / 4; ++k) s = dot4_(hr[k], wr[k], s);
    out[(size_t)b * V_ + v] = s + fc_b[v];
}

extern "C" void kernel_launch(void* const* d_in, const int* in_sizes, int n_in,
                              void* d_out, int out_size, void* d_ws, size_t ws_size,
                              hipStream_t stream) {
    const float* x     = (const float*)d_in[0];
    const float* w_ih0 = (const float*)d_in[1];
    const float* w_hh0 = (const float*)d_in[2];
    const float* b_ih0 = (const float*)d_in[3];
    const float* b_hh0 = (const float*)d_in[4];
    const float* w_ih1 = (const float*)d_in[5];
    const float* w_hh1 = (const float*)d_in[6];
    const float* b_ih1 = (const float*)d_in[7];
    const float* b_hh1 = (const float*)d_in[8];
    const float* fc_w  = (const float*)d_in[9];
    const float* fc_b  = (const float*)d_in[10];
    float* out = (float*)d_out;

    // ---- workspace carve-up ----
    char* p = (char*)d_ws;
    u16* Xswz    = (u16*)p; p += (size_t)512 * 32768 * 2;          // 32 MB
    u16* Out0swz = (u16*)p; p += (size_t)512 * 65536 * 2;          // 64 MB
    u16* WB0     = (u16*)p; p += (size_t)128 * 24 * 512 * 2;       // 3 MB
    u16* WB1     = (u16*)p; p += (size_t)128 * 32 * 512 * 2;       // 4 MB
    u32* Htag    = (u32*)p; p += (size_t)8 * 32768 * 4;            // 1 MB
    float* bsum0 = (float*)p; p += 2048 * 4;
    float* bsum1 = (float*)p; p += 2048 * 4;
    u32* bc      = (u32*)p;  p += 4 * 64 * 4;                      // 1 KB

    // ---- init + operand re-layout (graph-replayed each call) ----
    hipMemsetAsync(Htag, 0, (size_t)8 * 32768 * 4, stream);        // tag 0 == h(-1)=0 ready
    hipMemsetAsync(bc, 0, 4 * 64 * 4, stream);
    conv_x<<<65536, 256, 0, stream>>>(Xswz, x);
    conv_w<<<(2048 * 768) / 256, 256, 0, stream>>>(WB0, w_ih0, w_hh0, 256, 768);
    conv_w<<<(2048 * 1024) / 256, 256, 0, stream>>>(WB1, w_ih1, w_hh1, 512, 1024);
    vadd<<<8, 256, 0, stream>>>(bsum0, b_ih0, b_hh0, 2048);
    vadd<<<8, 256, 0, stream>>>(bsum1, b_ih1, b_hh1, 2048);

    // ---- persistent pipelined recurrence: one dispatch ----
    lstm_persistent<<<256, 256, 0, stream>>>(
        Xswz, Out0swz, WB0, WB1, bsum0, bsum1, Htag, out, bc);

    logits_kernel<<<B_, 256, 0, stream>>>(out + 98304, fc_w, fc_b, out);
}